// Round 9
// baseline (167.702 us; speedup 1.0000x reference)
//
#include <hip/hip_runtime.h>
#include <hip/hip_bf16.h>

// VectorQuantizer: B=64, C=64, H=32, W=32, K=1024
// d_in[0]: inputs  [B,C,H,W] fp32  (4,194,304)
// d_in[1]: weight  [K,C]     fp32  (65,536)
// d_out (float32, concat): quantized_st [4194304] | indices [65536] | loss [64]

#define VQ_C    64
#define VQ_K    1024
#define VQ_HW   1024
#define VQ_B    64
#define VQ_ROWS (VQ_B * VQ_HW)      // 65536
#define BLOCK   256
#define RPB     64                  // rows per block
#define GBLOCKS (VQ_ROWS / RPB)     // 1024 blocks
#define CHUNK   64                  // codes per LDS chunk
#define NCHUNK  (VQ_K / CHUNK)      // 16

// XOR-swizzled LDS float index for a [64][64] tile: row stride 64 floats,
// 16B slots rotated by row&15 -> tile reads are <=2-way bank conflicts.
__device__ __forceinline__ int SWZ(int row, int c) {
    return row * 64 + (((c >> 2) ^ (row & 15)) << 2) + (c & 3);
}

// ---- se2 precompute: ||e_k||^2, same fmaf chain as rounds 1-8 (bit-identical) ----
__global__ __launch_bounds__(BLOCK) void vq_se2_kernel(
    const float* __restrict__ w, float* __restrict__ se2g) {
    const int k = blockIdx.x * BLOCK + threadIdx.x;   // grid 4*256 = 1024
    const float* wr = w + (size_t)k * VQ_C;
    float s0 = 0.f, s1 = 0.f, s2 = 0.f, s3 = 0.f;
    #pragma unroll
    for (int c = 0; c < VQ_C; c += 4) {
        s0 = fmaf(wr[c + 0], wr[c + 0], s0);
        s1 = fmaf(wr[c + 1], wr[c + 1], s1);
        s2 = fmaf(wr[c + 2], wr[c + 2], s2);
        s3 = fmaf(wr[c + 3], wr[c + 3], s3);
    }
    se2g[k] = (s0 + s1) + (s2 + s3);
}

// ---------------- fused GEMM-tiled VQ: one block = 64 rows x all 1024 codes ----------------
__global__ __launch_bounds__(BLOCK, 4) void vq_gemm_kernel(
    const float* __restrict__ inp,   // [B,C,H,W]
    const float* __restrict__ w,     // [K,C]
    const float* __restrict__ se2g,  // [K]
    float* __restrict__ out_q,       // [B,C,H,W]
    float* __restrict__ out_idx,     // [B*H*W] as float
    float* __restrict__ partials)    // [GBLOCKS]
{
    __shared__ float xs [RPB * VQ_C];    // 16 KB  x tile (swizzled)
    __shared__ float wsm[CHUNK * VQ_C];  // 16 KB  w chunk (swizzled); reused for cand/bkf
    __shared__ float se2s[VQ_K];         // 4 KB;  reused as red[] in loss reduce

    const int tid = threadIdx.x;
    const int blk = blockIdx.x;
    const int b   = blk >> 4;            // 16 blocks per batch image
    const int hw0 = (blk & 15) * RPB;

    const int kt = tid & 15;             // code-thread 0..15
    const int rt = tid >> 4;             // row-group  0..15

    // ---- stage x tile: [64 rows][64 c], swizzled; coalesced global reads ----
    {
        const int row = tid & 63, cg = tid >> 6;
        const float* xin = inp + (size_t)b * (VQ_C * VQ_HW) + hw0 + row;
        #pragma unroll
        for (int p = 0; p < 16; ++p) {
            const int c = cg * 16 + p;
            xs[SWZ(row, c)] = xin[(size_t)c * VQ_HW];
        }
    }
    // ---- stage se2 ----
    #pragma unroll
    for (int i = 0; i < 4; ++i) se2s[i * BLOCK + tid] = se2g[i * BLOCK + tid];
    __syncthreads();

    // ---- per-thread row constants; sx with the EXACT stride-4 chain of rounds 1-8 ----
    int rowBase[4], rowRot[4];
    float sx[4];
    #pragma unroll
    for (int i = 0; i < 4; ++i) {
        const int row = rt * 4 + i;
        rowBase[i] = row * 64;
        rowRot[i]  = row & 15;
        float s0 = 0.f, s1 = 0.f, s2 = 0.f, s3 = 0.f;
        #pragma unroll
        for (int cs = 0; cs < 16; ++cs) {
            const float4 xf = *reinterpret_cast<const float4*>(
                &xs[rowBase[i] + ((cs ^ rowRot[i]) << 2)]);
            s0 = fmaf(xf.x, xf.x, s0);
            s1 = fmaf(xf.y, xf.y, s1);
            s2 = fmaf(xf.z, xf.z, s2);
            s3 = fmaf(xf.w, xf.w, s3);
        }
        sx[i] = (s0 + s1) + (s2 + s3);
    }

    int lcBase[4];
    #pragma unroll
    for (int j = 0; j < 4; ++j) lcBase[j] = (j * 16 + kt) * 64;
    const int lcRot = kt;   // (j*16+kt)&15 == kt

    float best[4]  = {3.402823466e38f, 3.402823466e38f, 3.402823466e38f, 3.402823466e38f};
    int   bestk[4] = {0, 0, 0, 0};

    // ---- main loop over 16 code-chunks ----
    #pragma unroll 1
    for (int chunk = 0; chunk < NCHUNK; ++chunk) {
        const int kbase = chunk * CHUNK;
        // stage w chunk [64 codes][64 c], swizzled; coalesced reads
        {
            const int c = tid & 63, lg = tid >> 6;
            const float* wg = w + (size_t)(kbase + lg * 16) * VQ_C + c;
            #pragma unroll
            for (int p = 0; p < 16; ++p)
                wsm[SWZ(lg * 16 + p, c)] = wg[(size_t)p * VQ_C];
        }
        __syncthreads();

        float acc[4][4] = {};
        #pragma unroll 4
        for (int cs = 0; cs < 16; ++cs) {
            float4 xf[4], wf[4];
            #pragma unroll
            for (int i = 0; i < 4; ++i)
                xf[i] = *reinterpret_cast<const float4*>(
                    &xs[rowBase[i] + ((cs ^ rowRot[i]) << 2)]);
            #pragma unroll
            for (int j = 0; j < 4; ++j)
                wf[j] = *reinterpret_cast<const float4*>(
                    &wsm[lcBase[j] + ((cs ^ lcRot) << 2)]);
            #pragma unroll
            for (int i = 0; i < 4; ++i) {
                #pragma unroll
                for (int j = 0; j < 4; ++j) {
                    acc[i][j] = fmaf(xf[i].x, wf[j].x, acc[i][j]);
                    acc[i][j] = fmaf(xf[i].y, wf[j].y, acc[i][j]);
                    acc[i][j] = fmaf(xf[i].z, wf[j].z, acc[i][j]);
                    acc[i][j] = fmaf(xf[i].w, wf[j].w, acc[i][j]);
                }
            }
        }

        // fold chunk into running argmin (explicit lowest-index tiebreak)
        #pragma unroll
        for (int j = 0; j < 4; ++j) {
            const int kAbs = kbase + j * 16 + kt;
            const float se2k = se2s[kAbs];
            #pragma unroll
            for (int i = 0; i < 4; ++i) {
                const float d = (sx[i] + se2k) - 2.f * acc[i][j];
                if (d < best[i] || (d == best[i] && kAbs < bestk[i])) {
                    best[i] = d; bestk[i] = kAbs;
                }
            }
        }
        __syncthreads();   // before next chunk overwrites wsm
    }

    // ---- cross-thread argmin per row (reuse wsm as scratch) ----
    float* cand_d = wsm;                        // [64][16]
    int*   cand_k = (int*)&wsm[1024];           // [64][16]
    int*   bkf    = (int*)&wsm[2048];           // [64]
    #pragma unroll
    for (int i = 0; i < 4; ++i) {
        const int row = rt * 4 + i;
        cand_d[row * 16 + kt] = best[i];
        cand_k[row * 16 + kt] = bestk[i];
    }
    __syncthreads();
    if (tid < RPB) {
        const int row = tid;
        float bd = cand_d[row * 16];
        int   bk = cand_k[row * 16];
        #pragma unroll
        for (int t = 1; t < 16; ++t) {
            const float d = cand_d[row * 16 + t];
            const int   k = cand_k[row * 16 + t];
            if (d < bd || (d == bd && k < bk)) { bd = d; bk = k; }
        }
        bkf[row] = bk;
        out_idx[blk * RPB + row] = (float)bk;
    }
    __syncthreads();

    // ---- epilogue: gather code, write quantized_st, accumulate loss ----
    float sdp = 0.f;
    {
        const int row = tid & 63, cg = tid >> 6;
        const int bk  = bkf[row];
        const float* qrow = w + (size_t)bk * VQ_C;
        float* outr = out_q + (size_t)b * (VQ_C * VQ_HW) + hw0 + row;
        #pragma unroll
        for (int p = 0; p < 16; ++p) {
            const int c = cg * 16 + p;
            const float xv = xs[SWZ(row, c)];
            const float qv = qrow[c];
            outr[(size_t)c * VQ_HW] = xv + (qv - xv);
            const float e = qv - xv;
            sdp = fmaf(e, e, sdp);
        }
    }
    float* red = se2s;   // reuse
    red[tid] = sdp;
    __syncthreads();
    #pragma unroll
    for (int s = BLOCK / 2; s > 0; s >>= 1) {
        if (tid < s) red[tid] += red[tid + s];
        __syncthreads();
    }
    if (tid == 0) partials[blk] = red[0];
}

__global__ __launch_bounds__(64) void vq_loss_kernel(
    const float* __restrict__ partials,  // [GBLOCKS], 16 blocks per b
    float* __restrict__ loss)            // [B]
{
    const int b = threadIdx.x;
    float s = 0.f;
    #pragma unroll
    for (int i = 0; i < 16; ++i) s += partials[b * 16 + i];
    const float L = s * (1.0f / 65536.0f);
    loss[b] = L + 0.25f * L;
}

// ---------------- fallback monolithic path (tiny ws; round-1 style) ----------------
__global__ __launch_bounds__(BLOCK) void vq_main_kernel(
    const float* __restrict__ inp,
    const float* __restrict__ w,
    float* __restrict__ out_q,
    float* __restrict__ out_idx,
    float* __restrict__ partials)
{
    __shared__ float se2s[VQ_K];
    __shared__ float red[BLOCK];
    const int tid = threadIdx.x;

    for (int k = tid; k < VQ_K; k += BLOCK) {
        const float* wr = w + k * VQ_C;
        float s0 = 0.f, s1 = 0.f, s2 = 0.f, s3 = 0.f;
        #pragma unroll
        for (int c = 0; c < VQ_C; c += 4) {
            s0 = fmaf(wr[c + 0], wr[c + 0], s0);
            s1 = fmaf(wr[c + 1], wr[c + 1], s1);
            s2 = fmaf(wr[c + 2], wr[c + 2], s2);
            s3 = fmaf(wr[c + 3], wr[c + 3], s3);
        }
        se2s[k] = (s0 + s1) + (s2 + s3);
    }
    __syncthreads();

    const int r  = blockIdx.x * BLOCK + tid;
    const int b  = r >> 10;
    const int hw = r & (VQ_HW - 1);

    const float* xin = inp + (size_t)b * (VQ_C * VQ_HW) + hw;
    float x[VQ_C];
    #pragma unroll
    for (int c = 0; c < VQ_C; ++c) x[c] = xin[(size_t)c * VQ_HW];

    float sx0 = 0.f, sx1 = 0.f, sx2 = 0.f, sx3 = 0.f;
    #pragma unroll
    for (int c = 0; c < VQ_C; c += 4) {
        sx0 = fmaf(x[c + 0], x[c + 0], sx0);
        sx1 = fmaf(x[c + 1], x[c + 1], sx1);
        sx2 = fmaf(x[c + 2], x[c + 2], sx2);
        sx3 = fmaf(x[c + 3], x[c + 3], sx3);
    }
    const float sx = (sx0 + sx1) + (sx2 + sx3);

    float best = 3.402823466e38f;
    int bestk = 0;
    for (int k = 0; k < VQ_K; ++k) {
        const float* wr = w + (size_t)k * VQ_C;
        float d0 = 0.f, d1 = 0.f, d2 = 0.f, d3 = 0.f;
        #pragma unroll
        for (int c = 0; c < VQ_C; c += 4) {
            d0 = fmaf(wr[c + 0], x[c + 0], d0);
            d1 = fmaf(wr[c + 1], x[c + 1], d1);
            d2 = fmaf(wr[c + 2], x[c + 2], d2);
            d3 = fmaf(wr[c + 3], x[c + 3], d3);
        }
        const float dot = (d0 + d1) + (d2 + d3);
        const float d = (sx + se2s[k]) - 2.f * dot;
        if (d < best) { best = d; bestk = k; }
    }

    const float* q = w + (size_t)bestk * VQ_C;
    float* outr = out_q + (size_t)b * (VQ_C * VQ_HW) + hw;
    float sd0 = 0.f, sd1 = 0.f, sd2 = 0.f, sd3 = 0.f;
    #pragma unroll
    for (int c = 0; c < VQ_C; c += 4) {
        float q0 = q[c + 0], q1 = q[c + 1], q2 = q[c + 2], q3 = q[c + 3];
        float x0 = x[c + 0], x1 = x[c + 1], x2 = x[c + 2], x3 = x[c + 3];
        outr[(size_t)(c + 0) * VQ_HW] = x0 + (q0 - x0);
        outr[(size_t)(c + 1) * VQ_HW] = x1 + (q1 - x1);
        outr[(size_t)(c + 2) * VQ_HW] = x2 + (q2 - x2);
        outr[(size_t)(c + 3) * VQ_HW] = x3 + (q3 - x3);
        float e0 = q0 - x0, e1 = q1 - x1, e2 = q2 - x2, e3 = q3 - x3;
        sd0 = fmaf(e0, e0, sd0);
        sd1 = fmaf(e1, e1, sd1);
        sd2 = fmaf(e2, e2, sd2);
        sd3 = fmaf(e3, e3, sd3);
    }
    out_idx[r] = (float)bestk;

    red[tid] = (sd0 + sd1) + (sd2 + sd3);
    __syncthreads();
    #pragma unroll
    for (int s = BLOCK / 2; s > 0; s >>= 1) {
        if (tid < s) red[tid] += red[tid + s];
        __syncthreads();
    }
    if (tid == 0) partials[blockIdx.x] = red[0];
}

__global__ __launch_bounds__(64) void vq_loss4_kernel(
    const float* __restrict__ partials, float* __restrict__ loss)
{
    const int b = threadIdx.x;
    const float s = (partials[4 * b + 0] + partials[4 * b + 1])
                  + (partials[4 * b + 2] + partials[4 * b + 3]);
    const float L = s * (1.0f / 65536.0f);
    loss[b] = L + 0.25f * L;
}

extern "C" void kernel_launch(void* const* d_in, const int* in_sizes, int n_in,
                              void* d_out, int out_size, void* d_ws, size_t ws_size,
                              hipStream_t stream) {
    const float* inp = (const float*)d_in[0];
    const float* w   = (const float*)d_in[1];

    float* out_q    = (float*)d_out;
    float* out_idx  = (float*)d_out + 4194304;
    float* out_loss = (float*)d_out + 4194304 + 65536;

    // ws: se2g[1024] | partials[1024]
    if (ws_size >= (size_t)(VQ_K + GBLOCKS) * sizeof(float)) {
        float* se2g     = (float*)d_ws;
        float* partials = se2g + VQ_K;
        vq_se2_kernel<<<VQ_K / BLOCK, BLOCK, 0, stream>>>(w, se2g);
        vq_gemm_kernel<<<GBLOCKS, BLOCK, 0, stream>>>(inp, w, se2g,
                                                      out_q, out_idx, partials);
        vq_loss_kernel<<<1, 64, 0, stream>>>(partials, out_loss);
    } else {
        float* partials = (float*)d_ws;  // 256 floats
        vq_main_kernel<<<VQ_ROWS / BLOCK, BLOCK, 0, stream>>>(inp, w, out_q, out_idx, partials);
        vq_loss4_kernel<<<1, 64, 0, stream>>>(partials, out_loss);
    }
}

// Round 10
// 150.559 us; speedup vs baseline: 1.1139x; 1.1139x over previous
//
#include <hip/hip_runtime.h>
#include <hip/hip_bf16.h>

// VectorQuantizer: B=64, C=64, H=32, W=32, K=1024
// d_out (float32, concat): quantized_st [4194304] | indices [65536] | loss [64]

#define VQ_C    64
#define VQ_K    1024
#define VQ_HW   1024
#define VQ_B    64
#define VQ_ROWS 65536
#define BLOCK   256
#define TROWS   128                 // rows per block
#define TCODES  128                 // codes per LDS chunk
#define NCHUNK  (VQ_K / TCODES)     // 8
#define XSTR    66                  // padded LDS row stride (floats): 2-way conflicts max
#define GBLOCKS (VQ_ROWS / TROWS)   // 512

// ---- se2 precompute: ||e_k||^2, same fmaf chain as rounds 1-9 (bit-identical) ----
__global__ __launch_bounds__(BLOCK) void vq_se2_kernel(
    const float* __restrict__ w, float* __restrict__ se2g) {
    const int k = blockIdx.x * BLOCK + threadIdx.x;   // grid 4*256 = 1024
    const float* wr = w + (size_t)k * VQ_C;
    float s0 = 0.f, s1 = 0.f, s2 = 0.f, s3 = 0.f;
    #pragma unroll
    for (int c = 0; c < VQ_C; c += 4) {
        s0 = fmaf(wr[c + 0], wr[c + 0], s0);
        s1 = fmaf(wr[c + 1], wr[c + 1], s1);
        s2 = fmaf(wr[c + 2], wr[c + 2], s2);
        s3 = fmaf(wr[c + 3], wr[c + 3], s3);
    }
    se2g[k] = (s0 + s1) + (s2 + s3);
}

// ---------------- T=8 register-tiled VQ: block = 128 rows x all 1024 codes ----------------
__global__ __launch_bounds__(BLOCK) void vq_gemm2_kernel(
    const float* __restrict__ inp,   // [B,C,H,W]
    const float* __restrict__ w,     // [K,C]
    const float* __restrict__ se2g,  // [K]
    float* __restrict__ out_q,
    float* __restrict__ out_idx,
    float* __restrict__ partials)    // [GBLOCKS]
{
    __shared__ float xs [TROWS * XSTR];    // 33 KB x tile (padded)
    __shared__ float wsb[TCODES * XSTR];   // 33 KB w chunk (padded); reused for merge
    __shared__ float se2s[VQ_K];           // 4 KB; reused as red[] in loss reduce
    __shared__ float sxs[TROWS];           // per-row ||x||^2

    const int tid = threadIdx.x;
    const int blk = blockIdx.x;
    const int b   = blk >> 3;              // 8 blocks per image
    const int hw0 = (blk & 7) * TROWS;

    // ---- stage x tile [128 rows][64 c] (coalesced: lanes = consecutive rows) ----
    {
        const int row = tid & 127, cg = tid >> 7;
        const float* xin = inp + (size_t)b * (VQ_C * VQ_HW) + hw0 + row;
        #pragma unroll
        for (int p = 0; p < 32; ++p) {
            const int c = cg * 32 + p;
            xs[row * XSTR + c] = xin[(size_t)c * VQ_HW];
        }
    }
    #pragma unroll
    for (int i = 0; i < 4; ++i) se2s[i * BLOCK + tid] = se2g[i * BLOCK + tid];
    __syncthreads();

    // ---- sx per row, EXACT stride-4 chain of rounds 1-8 (one thread per row) ----
    if (tid < TROWS) {
        const float* xr = &xs[tid * XSTR];
        float s0 = 0.f, s1 = 0.f, s2 = 0.f, s3 = 0.f;
        #pragma unroll
        for (int cs = 0; cs < 16; ++cs) {
            const float4 xf = *reinterpret_cast<const float4*>(&xr[cs * 4]);
            s0 = fmaf(xf.x, xf.x, s0);
            s1 = fmaf(xf.y, xf.y, s1);
            s2 = fmaf(xf.z, xf.z, s2);
            s3 = fmaf(xf.w, xf.w, s3);
        }
        sxs[tid] = (s0 + s1) + (s2 + s3);
    }

    // ---- prefetch chunk 0 of w into regs (coalesced: 16 lanes span one code row) ----
    const int cq = tid & 15, cg2 = tid >> 4;   // channel-quad, code-group
    float4 wreg[8];
    {
        const float* wg = w + (size_t)cg2 * VQ_C + cq * 4;
        #pragma unroll
        for (int p = 0; p < 8; ++p)
            wreg[p] = *reinterpret_cast<const float4*>(wg + (size_t)(p * 16) * VQ_C);
    }
    __syncthreads();   // sxs visible

    const int kt = tid & 15;
    const int rt = tid >> 4;

    float sxr[8];
    #pragma unroll
    for (int i = 0; i < 8; ++i) sxr[i] = sxs[rt * 8 + i];

    float best[8];
    int   bestk[8];
    #pragma unroll
    for (int i = 0; i < 8; ++i) { best[i] = 3.402823466e38f; bestk[i] = 0; }

    // ---- main loop over 8 code-chunks ----
    #pragma unroll 1
    for (int chunk = 0; chunk < NCHUNK; ++chunk) {
        const int kbase = chunk * TCODES;

        // write prefetched w chunk to LDS
        #pragma unroll
        for (int p = 0; p < 8; ++p)
            *reinterpret_cast<float4*>(&wsb[(p * 16 + cg2) * XSTR + cq * 4]) = wreg[p];
        __syncthreads();

        // prefetch next chunk (overlaps compute below)
        if (chunk + 1 < NCHUNK) {
            const float* wg = w + (size_t)(kbase + TCODES + cg2) * VQ_C + cq * 4;
            #pragma unroll
            for (int p = 0; p < 8; ++p)
                wreg[p] = *reinterpret_cast<const float4*>(wg + (size_t)(p * 16) * VQ_C);
        }

        // 8x8 register-tile dot accumulation (sequential fmaf chain per acc,
        // channels ascending — same order as round 9, which matched np exactly)
        float acc[8][8] = {};
        #pragma unroll 1
        for (int cs = 0; cs < 16; ++cs) {
            float4 xf[8], wf[8];
            #pragma unroll
            for (int i = 0; i < 8; ++i)
                xf[i] = *reinterpret_cast<const float4*>(
                    &xs[(rt * 8 + i) * XSTR + cs * 4]);
            #pragma unroll
            for (int j = 0; j < 8; ++j)
                wf[j] = *reinterpret_cast<const float4*>(
                    &wsb[(j * 16 + kt) * XSTR + cs * 4]);
            #pragma unroll
            for (int i = 0; i < 8; ++i) {
                #pragma unroll
                for (int j = 0; j < 8; ++j) {
                    acc[i][j] = fmaf(xf[i].x, wf[j].x, acc[i][j]);
                    acc[i][j] = fmaf(xf[i].y, wf[j].y, acc[i][j]);
                    acc[i][j] = fmaf(xf[i].z, wf[j].z, acc[i][j]);
                    acc[i][j] = fmaf(xf[i].w, wf[j].w, acc[i][j]);
                }
            }
        }

        // fold into running argmin (explicit lowest-index tiebreak == np.argmin)
        #pragma unroll
        for (int j = 0; j < 8; ++j) {
            const int   kAbs = kbase + j * 16 + kt;
            const float se2k = se2s[kAbs];
            #pragma unroll
            for (int i = 0; i < 8; ++i) {
                const float d = (sxr[i] + se2k) - 2.f * acc[i][j];
                if (d < best[i] || (d == best[i] && kAbs < bestk[i])) {
                    best[i] = d; bestk[i] = kAbs;
                }
            }
        }
        __syncthreads();   // before next chunk overwrites wsb
    }

    // ---- cross-thread argmin per row (reuse wsb as scratch) ----
    float* cand_d = wsb;                   // [128][16]
    int*   cand_k = (int*)&wsb[2048];      // [128][16]
    int*   bkf    = (int*)&wsb[4096];      // [128]
    #pragma unroll
    for (int i = 0; i < 8; ++i) {
        const int row = rt * 8 + i;
        cand_d[row * 16 + kt] = best[i];
        cand_k[row * 16 + kt] = bestk[i];
    }
    __syncthreads();
    if (tid < TROWS) {
        const int row = tid;
        float bd = cand_d[row * 16];
        int   bk = cand_k[row * 16];
        #pragma unroll
        for (int t = 1; t < 16; ++t) {
            const float d = cand_d[row * 16 + t];
            const int   k = cand_k[row * 16 + t];
            if (d < bd || (d == bd && k < bk)) { bd = d; bk = k; }
        }
        bkf[row] = bk;
        out_idx[blk * TROWS + row] = (float)bk;
    }
    __syncthreads();

    // ---- epilogue: gather code, write quantized_st, accumulate loss ----
    float sdp = 0.f;
    {
        const int row = tid & 127, cgE = tid >> 7;
        const int bk  = bkf[row];
        const float* qrow = w + (size_t)bk * VQ_C;
        float* outr = out_q + (size_t)b * (VQ_C * VQ_HW) + hw0 + row;
        #pragma unroll
        for (int p = 0; p < 32; ++p) {
            const int c = cgE * 32 + p;
            const float xv = xs[row * XSTR + c];
            const float qv = qrow[c];
            outr[(size_t)c * VQ_HW] = xv + (qv - xv);
            const float e = qv - xv;
            sdp = fmaf(e, e, sdp);
        }
    }
    float* red = se2s;   // reuse
    red[tid] = sdp;
    __syncthreads();
    #pragma unroll
    for (int s = BLOCK / 2; s > 0; s >>= 1) {
        if (tid < s) red[tid] += red[tid + s];
        __syncthreads();
    }
    if (tid == 0) partials[blk] = red[0];
}

__global__ __launch_bounds__(64) void vq_loss_kernel(
    const float* __restrict__ partials,  // [GBLOCKS], 8 blocks per b
    float* __restrict__ loss)            // [B]
{
    const int b = threadIdx.x;
    float s = 0.f;
    #pragma unroll
    for (int i = 0; i < 8; ++i) s += partials[b * 8 + i];
    const float L = s * (1.0f / 65536.0f);
    loss[b] = L + 0.25f * L;
}

// ---------------- fallback monolithic path (tiny ws; round-1 style) ----------------
__global__ __launch_bounds__(BLOCK) void vq_main_kernel(
    const float* __restrict__ inp,
    const float* __restrict__ w,
    float* __restrict__ out_q,
    float* __restrict__ out_idx,
    float* __restrict__ partials)
{
    __shared__ float se2s[VQ_K];
    __shared__ float red[BLOCK];
    const int tid = threadIdx.x;

    for (int k = tid; k < VQ_K; k += BLOCK) {
        const float* wr = w + k * VQ_C;
        float s0 = 0.f, s1 = 0.f, s2 = 0.f, s3 = 0.f;
        #pragma unroll
        for (int c = 0; c < VQ_C; c += 4) {
            s0 = fmaf(wr[c + 0], wr[c + 0], s0);
            s1 = fmaf(wr[c + 1], wr[c + 1], s1);
            s2 = fmaf(wr[c + 2], wr[c + 2], s2);
            s3 = fmaf(wr[c + 3], wr[c + 3], s3);
        }
        se2s[k] = (s0 + s1) + (s2 + s3);
    }
    __syncthreads();

    const int r  = blockIdx.x * BLOCK + tid;
    const int b  = r >> 10;
    const int hw = r & (VQ_HW - 1);

    const float* xin = inp + (size_t)b * (VQ_C * VQ_HW) + hw;
    float x[VQ_C];
    #pragma unroll
    for (int c = 0; c < VQ_C; ++c) x[c] = xin[(size_t)c * VQ_HW];

    float sx0 = 0.f, sx1 = 0.f, sx2 = 0.f, sx3 = 0.f;
    #pragma unroll
    for (int c = 0; c < VQ_C; c += 4) {
        sx0 = fmaf(x[c + 0], x[c + 0], sx0);
        sx1 = fmaf(x[c + 1], x[c + 1], sx1);
        sx2 = fmaf(x[c + 2], x[c + 2], sx2);
        sx3 = fmaf(x[c + 3], x[c + 3], sx3);
    }
    const float sx = (sx0 + sx1) + (sx2 + sx3);

    float best = 3.402823466e38f;
    int bestk = 0;
    for (int k = 0; k < VQ_K; ++k) {
        const float* wr = w + (size_t)k * VQ_C;
        float d0 = 0.f, d1 = 0.f, d2 = 0.f, d3 = 0.f;
        #pragma unroll
        for (int c = 0; c < VQ_C; c += 4) {
            d0 = fmaf(wr[c + 0], x[c + 0], d0);
            d1 = fmaf(wr[c + 1], x[c + 1], d1);
            d2 = fmaf(wr[c + 2], x[c + 2], d2);
            d3 = fmaf(wr[c + 3], x[c + 3], d3);
        }
        const float dot = (d0 + d1) + (d2 + d3);
        const float d = (sx + se2s[k]) - 2.f * dot;
        if (d < best) { best = d; bestk = k; }
    }

    const float* q = w + (size_t)bestk * VQ_C;
    float* outr = out_q + (size_t)b * (VQ_C * VQ_HW) + hw;
    float sd0 = 0.f, sd1 = 0.f, sd2 = 0.f, sd3 = 0.f;
    #pragma unroll
    for (int c = 0; c < VQ_C; c += 4) {
        float q0 = q[c + 0], q1 = q[c + 1], q2 = q[c + 2], q3 = q[c + 3];
        float x0 = x[c + 0], x1 = x[c + 1], x2 = x[c + 2], x3 = x[c + 3];
        outr[(size_t)(c + 0) * VQ_HW] = x0 + (q0 - x0);
        outr[(size_t)(c + 1) * VQ_HW] = x1 + (q1 - x1);
        outr[(size_t)(c + 2) * VQ_HW] = x2 + (q2 - x2);
        outr[(size_t)(c + 3) * VQ_HW] = x3 + (q3 - x3);
        float e0 = q0 - x0, e1 = q1 - x1, e2 = q2 - x2, e3 = q3 - x3;
        sd0 = fmaf(e0, e0, sd0);
        sd1 = fmaf(e1, e1, sd1);
        sd2 = fmaf(e2, e2, sd2);
        sd3 = fmaf(e3, e3, sd3);
    }
    out_idx[r] = (float)bestk;

    red[tid] = (sd0 + sd1) + (sd2 + sd3);
    __syncthreads();
    #pragma unroll
    for (int s = BLOCK / 2; s > 0; s >>= 1) {
        if (tid < s) red[tid] += red[tid + s];
        __syncthreads();
    }
    if (tid == 0) partials[blockIdx.x] = red[0];
}

__global__ __launch_bounds__(64) void vq_loss4_kernel(
    const float* __restrict__ partials, float* __restrict__ loss)
{
    const int b = threadIdx.x;
    const float s = (partials[4 * b + 0] + partials[4 * b + 1])
                  + (partials[4 * b + 2] + partials[4 * b + 3]);
    const float L = s * (1.0f / 65536.0f);
    loss[b] = L + 0.25f * L;
}

extern "C" void kernel_launch(void* const* d_in, const int* in_sizes, int n_in,
                              void* d_out, int out_size, void* d_ws, size_t ws_size,
                              hipStream_t stream) {
    const float* inp = (const float*)d_in[0];
    const float* w   = (const float*)d_in[1];

    float* out_q    = (float*)d_out;
    float* out_idx  = (float*)d_out + 4194304;
    float* out_loss = (float*)d_out + 4194304 + 65536;

    // ws: se2g[1024] | partials[512]
    if (ws_size >= (size_t)(VQ_K + GBLOCKS) * sizeof(float)) {
        float* se2g     = (float*)d_ws;
        float* partials = se2g + VQ_K;
        vq_se2_kernel<<<VQ_K / BLOCK, BLOCK, 0, stream>>>(w, se2g);
        vq_gemm2_kernel<<<GBLOCKS, BLOCK, 0, stream>>>(inp, w, se2g,
                                                       out_q, out_idx, partials);
        vq_loss_kernel<<<1, 64, 0, stream>>>(partials, out_loss);
    } else {
        float* partials = (float*)d_ws;  // 256 floats
        vq_main_kernel<<<VQ_ROWS / BLOCK, BLOCK, 0, stream>>>(inp, w, out_q, out_idx, partials);
        vq_loss4_kernel<<<1, 64, 0, stream>>>(partials, out_loss);
    }
}

// Round 11
// 149.613 us; speedup vs baseline: 1.1209x; 1.0063x over previous
//
#include <hip/hip_runtime.h>
#include <hip/hip_bf16.h>

// VectorQuantizer: B=64, C=64, H=32, W=32, K=1024
// d_out (float32, concat): quantized_st [4194304] | indices [65536] | loss [64]

#define VQ_C    64
#define VQ_K    1024
#define VQ_HW   1024
#define VQ_B    64
#define VQ_ROWS 65536
#define BLOCK   256
#define TROWS   128                 // rows per block
#define TCODES  128                 // codes per LDS chunk
#define NCHUNK  (VQ_K / TCODES)     // 8
#define XSTR    66                  // padded LDS row stride (floats): 2-way conflicts max
#define GBLOCKS (VQ_ROWS / TROWS)   // 512

// ---- se2 precompute: ||e_k||^2, same fmaf chain as rounds 1-10 (bit-identical) ----
__global__ __launch_bounds__(BLOCK) void vq_se2_kernel(
    const float* __restrict__ w, float* __restrict__ se2g) {
    const int k = blockIdx.x * BLOCK + threadIdx.x;   // grid 4*256 = 1024
    const float* wr = w + (size_t)k * VQ_C;
    float s0 = 0.f, s1 = 0.f, s2 = 0.f, s3 = 0.f;
    #pragma unroll
    for (int c = 0; c < VQ_C; c += 4) {
        s0 = fmaf(wr[c + 0], wr[c + 0], s0);
        s1 = fmaf(wr[c + 1], wr[c + 1], s1);
        s2 = fmaf(wr[c + 2], wr[c + 2], s2);
        s3 = fmaf(wr[c + 3], wr[c + 3], s3);
    }
    se2g[k] = (s0 + s1) + (s2 + s3);
}

// ---------------- T=8 register-tiled VQ: block = 128 rows x all 1024 codes ----------------
// __launch_bounds__(256, 2): LDS (72KB) caps us at 2 blocks/CU = 2 waves/EU anyway,
// so declare it -> VGPR budget 256 -> the 8x8 acc tile stays in registers (round 10
// spilled at the default cap of ~116 VGPRs: WRITE_SIZE 65.6MB of scratch traffic).
__global__ __launch_bounds__(BLOCK, 2) void vq_gemm2_kernel(
    const float* __restrict__ inp,   // [B,C,H,W]
    const float* __restrict__ w,     // [K,C]
    const float* __restrict__ se2g,  // [K]
    float* __restrict__ out_q,
    float* __restrict__ out_idx,
    float* __restrict__ partials)    // [GBLOCKS]
{
    __shared__ float xs [TROWS * XSTR];    // 33 KB x tile (padded)
    __shared__ float wsb[TCODES * XSTR];   // 33 KB w chunk (padded); reused for merge
    __shared__ float se2s[VQ_K];           // 4 KB; reused as red[] in loss reduce
    __shared__ float sxs[TROWS];           // per-row ||x||^2

    const int tid = threadIdx.x;
    const int blk = blockIdx.x;
    const int b   = blk >> 3;              // 8 blocks per image
    const int hw0 = (blk & 7) * TROWS;

    // ---- stage x tile [128 rows][64 c] (coalesced: lanes = consecutive rows) ----
    {
        const int row = tid & 127, cg = tid >> 7;
        const float* xin = inp + (size_t)b * (VQ_C * VQ_HW) + hw0 + row;
        #pragma unroll
        for (int p = 0; p < 32; ++p) {
            const int c = cg * 32 + p;
            xs[row * XSTR + c] = xin[(size_t)c * VQ_HW];
        }
    }
    #pragma unroll
    for (int i = 0; i < 4; ++i) se2s[i * BLOCK + tid] = se2g[i * BLOCK + tid];
    __syncthreads();

    // ---- sx per row, EXACT stride-4 chain of rounds 1-8 (one thread per row) ----
    if (tid < TROWS) {
        const float* xr = &xs[tid * XSTR];
        float s0 = 0.f, s1 = 0.f, s2 = 0.f, s3 = 0.f;
        #pragma unroll
        for (int cs = 0; cs < 16; ++cs) {
            const float4 xf = *reinterpret_cast<const float4*>(&xr[cs * 4]);
            s0 = fmaf(xf.x, xf.x, s0);
            s1 = fmaf(xf.y, xf.y, s1);
            s2 = fmaf(xf.z, xf.z, s2);
            s3 = fmaf(xf.w, xf.w, s3);
        }
        sxs[tid] = (s0 + s1) + (s2 + s3);
    }

    // ---- prefetch chunk 0 of w into regs (coalesced: 16 lanes span one code row) ----
    const int cq = tid & 15, cg2 = tid >> 4;   // channel-quad, code-group
    float4 wreg[8];
    {
        const float* wg = w + (size_t)cg2 * VQ_C + cq * 4;
        #pragma unroll
        for (int p = 0; p < 8; ++p)
            wreg[p] = *reinterpret_cast<const float4*>(wg + (size_t)(p * 16) * VQ_C);
    }
    __syncthreads();   // sxs visible

    const int kt = tid & 15;
    const int rt = tid >> 4;

    float sxr[8];
    #pragma unroll
    for (int i = 0; i < 8; ++i) sxr[i] = sxs[rt * 8 + i];

    float best[8];
    int   bestk[8];
    #pragma unroll
    for (int i = 0; i < 8; ++i) { best[i] = 3.402823466e38f; bestk[i] = 0; }

    // ---- main loop over 8 code-chunks ----
    #pragma unroll 1
    for (int chunk = 0; chunk < NCHUNK; ++chunk) {
        const int kbase = chunk * TCODES;

        // write prefetched w chunk to LDS
        #pragma unroll
        for (int p = 0; p < 8; ++p)
            *reinterpret_cast<float4*>(&wsb[(p * 16 + cg2) * XSTR + cq * 4]) = wreg[p];
        __syncthreads();

        // prefetch next chunk (overlaps compute below)
        if (chunk + 1 < NCHUNK) {
            const float* wg = w + (size_t)(kbase + TCODES + cg2) * VQ_C + cq * 4;
            #pragma unroll
            for (int p = 0; p < 8; ++p)
                wreg[p] = *reinterpret_cast<const float4*>(wg + (size_t)(p * 16) * VQ_C);
        }

        // 8x8 register-tile dot accumulation (sequential fmaf chain per acc,
        // channels ascending — same order as rounds 9-10, matched np exactly)
        float acc[8][8] = {};
        #pragma unroll 1
        for (int cs = 0; cs < 16; ++cs) {
            float4 xf[8], wf[8];
            #pragma unroll
            for (int i = 0; i < 8; ++i)
                xf[i] = *reinterpret_cast<const float4*>(
                    &xs[(rt * 8 + i) * XSTR + cs * 4]);
            #pragma unroll
            for (int j = 0; j < 8; ++j)
                wf[j] = *reinterpret_cast<const float4*>(
                    &wsb[(j * 16 + kt) * XSTR + cs * 4]);
            #pragma unroll
            for (int i = 0; i < 8; ++i) {
                #pragma unroll
                for (int j = 0; j < 8; ++j) {
                    acc[i][j] = fmaf(xf[i].x, wf[j].x, acc[i][j]);
                    acc[i][j] = fmaf(xf[i].y, wf[j].y, acc[i][j]);
                    acc[i][j] = fmaf(xf[i].z, wf[j].z, acc[i][j]);
                    acc[i][j] = fmaf(xf[i].w, wf[j].w, acc[i][j]);
                }
            }
        }

        // fold into running argmin (explicit lowest-index tiebreak == np.argmin)
        #pragma unroll
        for (int j = 0; j < 8; ++j) {
            const int   kAbs = kbase + j * 16 + kt;
            const float se2k = se2s[kAbs];
            #pragma unroll
            for (int i = 0; i < 8; ++i) {
                const float d = (sxr[i] + se2k) - 2.f * acc[i][j];
                if (d < best[i] || (d == best[i] && kAbs < bestk[i])) {
                    best[i] = d; bestk[i] = kAbs;
                }
            }
        }
        __syncthreads();   // before next chunk overwrites wsb
    }

    // ---- cross-thread argmin per row (reuse wsb as scratch) ----
    float* cand_d = wsb;                   // [128][16]
    int*   cand_k = (int*)&wsb[2048];      // [128][16]
    int*   bkf    = (int*)&wsb[4096];      // [128]
    #pragma unroll
    for (int i = 0; i < 8; ++i) {
        const int row = rt * 8 + i;
        cand_d[row * 16 + kt] = best[i];
        cand_k[row * 16 + kt] = bestk[i];
    }
    __syncthreads();
    if (tid < TROWS) {
        const int row = tid;
        float bd = cand_d[row * 16];
        int   bk = cand_k[row * 16];
        #pragma unroll
        for (int t = 1; t < 16; ++t) {
            const float d = cand_d[row * 16 + t];
            const int   k = cand_k[row * 16 + t];
            if (d < bd || (d == bd && k < bk)) { bd = d; bk = k; }
        }
        bkf[row] = bk;
        out_idx[blk * TROWS + row] = (float)bk;
    }
    __syncthreads();

    // ---- epilogue: gather code, write quantized_st, accumulate loss ----
    float sdp = 0.f;
    {
        const int row = tid & 127, cgE = tid >> 7;
        const int bk  = bkf[row];
        const float* qrow = w + (size_t)bk * VQ_C;
        float* outr = out_q + (size_t)b * (VQ_C * VQ_HW) + hw0 + row;
        #pragma unroll
        for (int p = 0; p < 32; ++p) {
            const int c = cgE * 32 + p;
            const float xv = xs[row * XSTR + c];
            const float qv = qrow[c];
            outr[(size_t)c * VQ_HW] = xv + (qv - xv);
            const float e = qv - xv;
            sdp = fmaf(e, e, sdp);
        }
    }
    float* red = se2s;   // reuse
    red[tid] = sdp;
    __syncthreads();
    #pragma unroll
    for (int s = BLOCK / 2; s > 0; s >>= 1) {
        if (tid < s) red[tid] += red[tid + s];
        __syncthreads();
    }
    if (tid == 0) partials[blk] = red[0];
}

__global__ __launch_bounds__(64) void vq_loss_kernel(
    const float* __restrict__ partials,  // [GBLOCKS], 8 blocks per b
    float* __restrict__ loss)            // [B]
{
    const int b = threadIdx.x;
    float s = 0.f;
    #pragma unroll
    for (int i = 0; i < 8; ++i) s += partials[b * 8 + i];
    const float L = s * (1.0f / 65536.0f);
    loss[b] = L + 0.25f * L;
}

// ---------------- fallback monolithic path (tiny ws; round-1 style) ----------------
__global__ __launch_bounds__(BLOCK) void vq_main_kernel(
    const float* __restrict__ inp,
    const float* __restrict__ w,
    float* __restrict__ out_q,
    float* __restrict__ out_idx,
    float* __restrict__ partials)
{
    __shared__ float se2s[VQ_K];
    __shared__ float red[BLOCK];
    const int tid = threadIdx.x;

    for (int k = tid; k < VQ_K; k += BLOCK) {
        const float* wr = w + k * VQ_C;
        float s0 = 0.f, s1 = 0.f, s2 = 0.f, s3 = 0.f;
        #pragma unroll
        for (int c = 0; c < VQ_C; c += 4) {
            s0 = fmaf(wr[c + 0], wr[c + 0], s0);
            s1 = fmaf(wr[c + 1], wr[c + 1], s1);
            s2 = fmaf(wr[c + 2], wr[c + 2], s2);
            s3 = fmaf(wr[c + 3], wr[c + 3], s3);
        }
        se2s[k] = (s0 + s1) + (s2 + s3);
    }
    __syncthreads();

    const int r  = blockIdx.x * BLOCK + tid;
    const int b  = r >> 10;
    const int hw = r & (VQ_HW - 1);

    const float* xin = inp + (size_t)b * (VQ_C * VQ_HW) + hw;
    float x[VQ_C];
    #pragma unroll
    for (int c = 0; c < VQ_C; ++c) x[c] = xin[(size_t)c * VQ_HW];

    float sx0 = 0.f, sx1 = 0.f, sx2 = 0.f, sx3 = 0.f;
    #pragma unroll
    for (int c = 0; c < VQ_C; c += 4) {
        sx0 = fmaf(x[c + 0], x[c + 0], sx0);
        sx1 = fmaf(x[c + 1], x[c + 1], sx1);
        sx2 = fmaf(x[c + 2], x[c + 2], sx2);
        sx3 = fmaf(x[c + 3], x[c + 3], sx3);
    }
    const float sx = (sx0 + sx1) + (sx2 + sx3);

    float best = 3.402823466e38f;
    int bestk = 0;
    for (int k = 0; k < VQ_K; ++k) {
        const float* wr = w + (size_t)k * VQ_C;
        float d0 = 0.f, d1 = 0.f, d2 = 0.f, d3 = 0.f;
        #pragma unroll
        for (int c = 0; c < VQ_C; c += 4) {
            d0 = fmaf(wr[c + 0], x[c + 0], d0);
            d1 = fmaf(wr[c + 1], x[c + 1], d1);
            d2 = fmaf(wr[c + 2], x[c + 2], d2);
            d3 = fmaf(wr[c + 3], x[c + 3], d3);
        }
        const float dot = (d0 + d1) + (d2 + d3);
        const float d = (sx + se2s[k]) - 2.f * dot;
        if (d < best) { best = d; bestk = k; }
    }

    const float* q = w + (size_t)bestk * VQ_C;
    float* outr = out_q + (size_t)b * (VQ_C * VQ_HW) + hw;
    float sd0 = 0.f, sd1 = 0.f, sd2 = 0.f, sd3 = 0.f;
    #pragma unroll
    for (int c = 0; c < VQ_C; c += 4) {
        float q0 = q[c + 0], q1 = q[c + 1], q2 = q[c + 2], q3 = q[c + 3];
        float x0 = x[c + 0], x1 = x[c + 1], x2 = x[c + 2], x3 = x[c + 3];
        outr[(size_t)(c + 0) * VQ_HW] = x0 + (q0 - x0);
        outr[(size_t)(c + 1) * VQ_HW] = x1 + (q1 - x1);
        outr[(size_t)(c + 2) * VQ_HW] = x2 + (q2 - x2);
        outr[(size_t)(c + 3) * VQ_HW] = x3 + (q3 - x3);
        float e0 = q0 - x0, e1 = q1 - x1, e2 = q2 - x2, e3 = q3 - x3;
        sd0 = fmaf(e0, e0, sd0);
        sd1 = fmaf(e1, e1, sd1);
        sd2 = fmaf(e2, e2, sd2);
        sd3 = fmaf(e3, e3, sd3);
    }
    out_idx[r] = (float)bestk;

    red[tid] = (sd0 + sd1) + (sd2 + sd3);
    __syncthreads();
    #pragma unroll
    for (int s = BLOCK / 2; s > 0; s >>= 1) {
        if (tid < s) red[tid] += red[tid + s];
        __syncthreads();
    }
    if (tid == 0) partials[blockIdx.x] = red[0];
}

__global__ __launch_bounds__(64) void vq_loss4_kernel(
    const float* __restrict__ partials, float* __restrict__ loss)
{
    const int b = threadIdx.x;
    const float s = (partials[4 * b + 0] + partials[4 * b + 1])
                  + (partials[4 * b + 2] + partials[4 * b + 3]);
    const float L = s * (1.0f / 65536.0f);
    loss[b] = L + 0.25f * L;
}

extern "C" void kernel_launch(void* const* d_in, const int* in_sizes, int n_in,
                              void* d_out, int out_size, void* d_ws, size_t ws_size,
                              hipStream_t stream) {
    const float* inp = (const float*)d_in[0];
    const float* w   = (const float*)d_in[1];

    float* out_q    = (float*)d_out;
    float* out_idx  = (float*)d_out + 4194304;
    float* out_loss = (float*)d_out + 4194304 + 65536;

    // ws: se2g[1024] | partials[512]
    if (ws_size >= (size_t)(VQ_K + GBLOCKS) * sizeof(float)) {
        float* se2g     = (float*)d_ws;
        float* partials = se2g + VQ_K;
        vq_se2_kernel<<<VQ_K / BLOCK, BLOCK, 0, stream>>>(w, se2g);
        vq_gemm2_kernel<<<GBLOCKS, BLOCK, 0, stream>>>(inp, w, se2g,
                                                       out_q, out_idx, partials);
        vq_loss_kernel<<<1, 64, 0, stream>>>(partials, out_loss);
    } else {
        float* partials = (float*)d_ws;  // 256 floats
        vq_main_kernel<<<VQ_ROWS / BLOCK, BLOCK, 0, stream>>>(inp, w, out_q, out_idx, partials);
        vq_loss4_kernel<<<1, 64, 0, stream>>>(partials, out_loss);
    }
}